// Round 5
// baseline (185.221 us; speedup 1.0000x reference)
//
#include <hip/hip_runtime.h>
#include <hip/hip_cooperative_groups.h>
#include <math.h>

// out[b] = (1^T · Π_d C_d · P) · Π_d x[b,d] + bias — per-row scalars commute
// out of the batch-independent matrix chain.
//
// ROUND 12: ONE cooperative kernel (hipLaunchCooperativeKernel — blessed by
// the harness). Rounds 9-11 proved the region is stuck at ~22 us vs a ~13 us
// floor; the residue is structural: 2 launch gaps + mps_scale + stream tail.
// Design (512 blocks x 256 thr, 2/CU co-resident; 26 KB LDS, VGPR now free):
//   blocks 0-31: verified chain fold (pre[16] up-front core loads) ->
//     partials -> flag fan-in (only block 0's 4 waves spin: proven safe;
//     round-3's 8192-wave spin storm = 934 us, never again) -> block 0
//     folds 32 partials in wave-0 regs, projects, writes pE to ws.
//   blocks 32-511: grid-stride 2048 row-units (4 rows/unit, 1/wave),
//     write prodbuf. 8 waves/CU x 8 KiB outstanding saturates HBM.
//   ONE grid.sync() (512 arrivals; all flags/pE precede it; no thread
//     returns early -> no deadlock), then all blocks write out:
//     131072 float4 == 1/thread at B=8192.
// Row products underflow fp32 to 0 exactly as the reference (absmax 0.0).

namespace cg = cooperative_groups;

#define DFEAT 2048
#define R 16
#define NR2 256               // R*R
#define OUTD 64
#define CHUNK 64              // cores folded per chain block
#define NCHUNK (DFEAT / CHUNK)    // 32 chain blocks
#define MAGIC 0x7E57C0DE
#define NBLK 512
#define NSTREAM (NBLK - NCHUNK)   // 480 streaming blocks

// (Arow · B)[c0..c0+3]: Arow = 16 LDS floats (4x ds_read_b128), B = 16x16
// row-major LDS matrix. All FMA, no barriers. (verbatim)
__device__ __forceinline__ float4 rowmul(const float* Arow, const float* B,
                                         int c0) {
    float4 acc = {0.f, 0.f, 0.f, 0.f};
    const float4* a4 = (const float4*)Arow;
#pragma unroll
    for (int kk = 0; kk < 4; ++kk) {
        const float4 av = a4[kk];
        const float4 b0 = *(const float4*)&B[(4 * kk + 0) * 16 + c0];
        const float4 b1 = *(const float4*)&B[(4 * kk + 1) * 16 + c0];
        const float4 b2 = *(const float4*)&B[(4 * kk + 2) * 16 + c0];
        const float4 b3 = *(const float4*)&B[(4 * kk + 3) * 16 + c0];
        acc.x = fmaf(av.x, b0.x, fmaf(av.y, b1.x, fmaf(av.z, b2.x, fmaf(av.w, b3.x, acc.x))));
        acc.y = fmaf(av.x, b0.y, fmaf(av.y, b1.y, fmaf(av.z, b2.y, fmaf(av.w, b3.y, acc.y))));
        acc.z = fmaf(av.x, b0.z, fmaf(av.y, b1.z, fmaf(av.z, b2.z, fmaf(av.w, b3.z, acc.z))));
        acc.w = fmaf(av.x, b0.w, fmaf(av.y, b1.w, fmaf(av.z, b2.w, fmaf(av.w, b3.w, acc.w))));
    }
    return acc;
}

__global__ __launch_bounds__(256) void mps_coop(const float* __restrict__ cores,
                                                const float* __restrict__ proj,
                                                const float* __restrict__ x,
                                                const float* __restrict__ bias,
                                                float* __restrict__ out,
                                                float* __restrict__ prodbuf,
                                                float* __restrict__ partials,
                                                int* __restrict__ flags,
                                                float* __restrict__ pE,
                                                int B) {
    __shared__ __align__(16) float Bb[4][2][NR2];   // 8 KB per-wave core pp
    __shared__ __align__(16) float Aw[4][2][NR2];   // 8 KB per-wave A pp
    __shared__ __align__(16) float F[2][NR2];       // 2 KB combine pp
    __shared__ __align__(16) float Pt[8 * NR2];     // 8 KB partial stage

    const int tid  = threadIdx.x;
    const int wave = tid >> 6, lane = tid & 63;
    const int bid  = blockIdx.x;

    if (bid >= NCHUNK) {
        // ============ streaming block: grid-stride row units ===============
        const int nunits = B >> 2;                   // 4 rows per unit
        for (int u = bid - NCHUNK; u < nunits; u += NSTREAM) {
            const int row = u * 4 + wave;
            const float4* xr = (const float4*)(x + (size_t)row * DFEAT);
            float prod = 1.f;
#pragma unroll
            for (int it = 0; it < DFEAT / (64 * 4); ++it) {  // 8x 1KiB/instr
                float4 v = xr[it * 64 + lane];
                prod *= (v.x * v.y) * (v.z * v.w);
            }
#pragma unroll
            for (int off = 32; off > 0; off >>= 1)           // wave product
                prod *= __shfl_xor(prod, off);
            if (lane == 0) prodbuf[row] = prod;
        }
    } else {
        // ==================== chain block (bid < 32) =======================
        const int ri = lane >> 2;         // row 0..15 (this lane's A/F row)
        const int c0 = (lane & 3) << 2;   // col base 0,4,8,12
        const size_t d0 = (size_t)bid * CHUNK;

        // ALL 16 cores loaded up front into registers (one latency exposure).
        const float* gw = cores + (d0 + 16 * wave) * NR2;
        float4 pre[16];
#pragma unroll
        for (int t = 0; t < 16; ++t)
            pre[t] = *(const float4*)&gw[(size_t)t * NR2 + lane * 4];

        *(float4*)&Aw[wave][0][lane * 4] = pre[0];     // A = core0
        int cur = 0;
#pragma unroll
        for (int t = 1; t < 16; ++t) {    // 15 multiplies -> result in buf 1
            *(float4*)&Bb[wave][t & 1][lane * 4] = pre[t];
            float4 r = rowmul(&Aw[wave][cur][ri * 16], &Bb[wave][t & 1][0], c0);
            *(float4*)&Aw[wave][cur ^ 1][ri * 16 + c0] = r;
            cur ^= 1;
        }
        __syncthreads();                  // all 4 wave-products ready

        // ---- wave 0 combines: F = Aw0 x Aw1 x Aw2 x Aw3 ----
        if (wave == 0) {
            *(float4*)&F[0][ri * 16 + c0] =
                *(const float4*)&Aw[0][1][ri * 16 + c0];
            int cc = 0;
            for (int w = 1; w < 4; ++w) {
                float4 r = rowmul(&F[cc][ri * 16], &Aw[w][1][0], c0);
                *(float4*)&F[cc ^ 1][ri * 16 + c0] = r;
                cc ^= 1;
            }
        }
        __syncthreads();
        const int i = tid >> 4, j = tid & 15;
        const float v = F[1][tid];        // element (i,j) of chunk product

        if (bid != 0) {
            // ---- producer: publish partial, release flag ----
            partials[bid * NR2 + tid] = v;
            __syncthreads();              // block stores complete at L2
            if (tid == 0)
                __hip_atomic_store(&flags[bid], MAGIC,
                                   __ATOMIC_RELEASE, __HIP_MEMORY_SCOPE_AGENT);
            // fall through to grid.sync()
        } else {
            // ---- block 0: own partial into LDS slot 0 (transposed) ----
            Pt[0 * 256 + j * 16 + i] = v;

            // acquire-spin for producers 1..31 — ONLY these 4 waves spin.
            {
                const int f = 1 + (tid % (NCHUNK - 1));
                while (__hip_atomic_load(&flags[f], __ATOMIC_ACQUIRE,
                                         __HIP_MEMORY_SCOPE_AGENT) != MAGIC) { }
            }
            __syncthreads();

            // ---- 4 rounds: stage 8 partials transposed + wave-0 fold ----
            float w = 1.f;
            int E = 0;
            for (int rr = 0; rr < 4; ++rr) {
#pragma unroll
                for (int q = 0; q < 2; ++q) {          // 512 float4 / round
                    const int idx = q * 256 + tid;
                    const int flat = idx * 4;
                    const int s = flat >> 8;           // local slot 0..7
                    if (rr > 0 || s > 0) {             // slot 0 of rr=0 = own
                        float4 p4 = ((const float4*)(partials +
                                       (size_t)(8 * rr) * NR2))[idx];
                        const int e = flat & 255;
                        const int k = e >> 4, j0 = e & 15;
                        Pt[s * 256 + (j0 + 0) * 16 + k] = p4.x;
                        Pt[s * 256 + (j0 + 1) * 16 + k] = p4.y;
                        Pt[s * 256 + (j0 + 2) * 16 + k] = p4.z;
                        Pt[s * 256 + (j0 + 3) * 16 + k] = p4.w;
                    }
                }
                __syncthreads();
                if (tid < 64) {           // wave-0 register fold, 8 per round
                    const int jj = tid & 15, q = tid >> 4;
                    for (int s = 0; s < 8; ++s) {
                        const float4 pr =
                            *(const float4*)&Pt[s * 256 + jj * 16 + 4 * q];
                        float sum;
                        sum = __shfl(w, 4 * q + 0) * pr.x;
                        sum = fmaf(__shfl(w, 4 * q + 1), pr.y, sum);
                        sum = fmaf(__shfl(w, 4 * q + 2), pr.z, sum);
                        sum = fmaf(__shfl(w, 4 * q + 3), pr.w, sum);
                        sum += __shfl_xor(sum, 16);
                        sum += __shfl_xor(sum, 32);
                        w = sum;
                    }
                    float m = fabsf(w);    // exact pow2 renorm, once/round
#pragma unroll
                    for (int off = 1; off <= 8; off <<= 1)
                        m = fmaxf(m, __shfl_xor(m, off));
                    if (m > 0.f) {
                        int e2 = 0;
                        (void)frexpf(m, &e2);
                        w = ldexpf(w, -e2);
                        E += e2;
                    }
                }
                __syncthreads();
            }

            if (tid < 64) {
                float p = 0.f;            // p[o] = sum_k w[k] * proj[k][o]
#pragma unroll
                for (int k = 0; k < R; ++k)
                    p = fmaf(__shfl(w, k), proj[k * OUTD + tid], p);
                pE[tid] = p;
                if (tid == 0) ((int*)pE)[OUTD] = E;
            }
        }
    }

    // ======================= ONE grid-wide barrier =========================
    cg::this_grid().sync();               // pE + prodbuf now globally visible

    // ---- epilogue: out[b][o] = ldexp(pE[o]*prod[b],E)+bias[o], 2 MB ----
    const int E = ((const int*)pE)[OUTD];
    const float4* pE4 = (const float4*)pE;
    const float4* b4  = (const float4*)bias;
    float4* o4 = (float4*)out;
    const int total4 = B * (OUTD / 4);    // 131072 at B=8192 == grid threads
    for (int idx = bid * 256 + tid; idx < total4; idx += NBLK * 256) {
        const int row = idx >> 4;         // 16 float4 per row
        const int c4  = idx & 15;
        const float pr = prodbuf[row];
        const float4 pe = pE4[c4];
        const float4 bb = b4[c4];
        float4 r;
        r.x = ldexpf(pe.x * pr, E) + bb.x;
        r.y = ldexpf(pe.y * pr, E) + bb.y;
        r.z = ldexpf(pe.z * pr, E) + bb.z;
        r.w = ldexpf(pe.w * pr, E) + bb.w;
        o4[idx] = r;
    }
}

// ---------------------------------------------------------------------------
extern "C" void kernel_launch(void* const* d_in, const int* in_sizes, int n_in,
                              void* d_out, int out_size, void* d_ws, size_t ws_size,
                              hipStream_t stream) {
    const float* inputs = (const float*)d_in[0];   // (B, 2048) fp32
    const float* cores  = (const float*)d_in[1];   // (2048, 16, 16) fp32
    const float* proj   = (const float*)d_in[2];   // (16, 64) fp32
    const float* bias   = (const float*)d_in[3];   // (64,) fp32
    float* out = (float*)d_out;                    // (B, 64) fp32

    const int B = in_sizes[0] / DFEAT;             // 8192

    // ws layout (16B aligned): prodbuf | partials | pE (64f + E) | flags
    float* prodbuf  = (float*)d_ws;                // B floats (32 KiB)
    float* partials = prodbuf + B;                 // 32*256 floats (32 KiB)
    float* pE    = partials + NCHUNK * NR2;        // 64 floats + int E (+pad)
    int*   flags = (int*)(pE + 68);                // 32 ints; harness poison
                                                   // != MAGIC each replay

    void* args[] = {(void*)&cores, (void*)&proj, (void*)&inputs, (void*)&bias,
                    (void*)&out, (void*)&prodbuf, (void*)&partials,
                    (void*)&flags, (void*)&pE, (void*)&B};
    hipLaunchCooperativeKernel((const void*)mps_coop, dim3(NBLK), dim3(256),
                               args, 0, stream);
}

// Round 6
// 102.959 us; speedup vs baseline: 1.7990x; 1.7990x over previous
//
#include <hip/hip_runtime.h>
#include <math.h>

// out[b] = (1^T · Π_d C_d · P) · Π_d x[b,d] + bias — per-row scalars commute
// out of the batch-independent matrix chain.
//
// ROUND 13: revert to VERIFIED round-4 two-kernel structure (104.8 us).
// Round-5's cooperative grid.sync was an ~88 us mass-spin barrier (VALUBusy
// 1%, HBM 5%) — cg sync joins mass flag-spins on the banned list. Learned:
// FETCH 34 MB < 64 MB input -> input is ~half L3-resident across replays.
//
// THIS ROUND: LDS 26 KB -> 18 KB by aliasing Pt (block-0 partial stage, 8 KB)
// onto the dead Bb fold buffers (lifetimes disjoint: fold -> barrier ->
// combine -> v=F[1][tid] all precede the first Pt write). 6 -> 8 blocks/CU
// => all 2080 blocks of the fused kernel co-resident in ONE dispatch wave
// (was 1536 + a 544-block tail adding ~3 us of stream time). mps_scale
// vectorized to one float4/thread (512 blocks).
// Row products underflow fp32 to 0 exactly as the reference (absmax 0.0).

#define DFEAT 2048
#define R 16
#define NR2 256               // R*R
#define OUTD 64
#define CHUNK 64              // cores folded per chain block
#define NCHUNK (DFEAT / CHUNK)    // 32 chain blocks
#define MAGIC 0x7E57C0DE

// (Arow · B)[c0..c0+3]: Arow = 16 LDS floats (4x ds_read_b128), B = 16x16
// row-major LDS matrix. All FMA, no barriers. (verbatim)
__device__ __forceinline__ float4 rowmul(const float* Arow, const float* B,
                                         int c0) {
    float4 acc = {0.f, 0.f, 0.f, 0.f};
    const float4* a4 = (const float4*)Arow;
#pragma unroll
    for (int kk = 0; kk < 4; ++kk) {
        const float4 av = a4[kk];
        const float4 b0 = *(const float4*)&B[(4 * kk + 0) * 16 + c0];
        const float4 b1 = *(const float4*)&B[(4 * kk + 1) * 16 + c0];
        const float4 b2 = *(const float4*)&B[(4 * kk + 2) * 16 + c0];
        const float4 b3 = *(const float4*)&B[(4 * kk + 3) * 16 + c0];
        acc.x = fmaf(av.x, b0.x, fmaf(av.y, b1.x, fmaf(av.z, b2.x, fmaf(av.w, b3.x, acc.x))));
        acc.y = fmaf(av.x, b0.y, fmaf(av.y, b1.y, fmaf(av.z, b2.y, fmaf(av.w, b3.y, acc.y))));
        acc.z = fmaf(av.x, b0.z, fmaf(av.y, b1.z, fmaf(av.z, b2.z, fmaf(av.w, b3.z, acc.z))));
        acc.w = fmaf(av.x, b0.w, fmaf(av.y, b1.w, fmaf(av.z, b2.w, fmaf(av.w, b3.w, acc.w))));
    }
    return acc;
}

__global__ __launch_bounds__(256) void mps_fused(const float* __restrict__ cores,
                                                 const float* __restrict__ proj,
                                                 const float* __restrict__ x,
                                                 float* __restrict__ prodbuf,
                                                 float* __restrict__ partials,
                                                 int* __restrict__ flags,
                                                 float* __restrict__ pE,
                                                 int B) {
    // 18 KB unified LDS pool -> 8 blocks/CU (wave-limited), 2048 co-resident.
    //   Bb = S[0    .. 2047]  (4 waves x 2 bufs x 256)  — core ping-pong
    //   Aw = S[2048 .. 4095]  (4 waves x 2 bufs x 256)  — A ping-pong
    //   F  = S[4096 .. 4607]  (2 bufs x 256)            — combine ping-pong
    //   Pt = S[0    .. 2047]  ALIASES Bb (dead after fold; lifetimes disjoint)
    __shared__ __align__(16) float S[4608];
    float* Bbase = S;
    float* Abase = S + 2048;
    float* Fbase = S + 4096;
    float* Pt    = S;                     // alias: block-0 only, post-fold

    const int tid  = threadIdx.x;
    const int wave = tid >> 6, lane = tid & 63;

    if (blockIdx.x >= NCHUNK) {
        // ================= row block: streaming product, no waits ==========
        const int row = (blockIdx.x - NCHUNK) * 4 + wave;
        if (row >= B) return;
        const float4* xr = (const float4*)(x + (size_t)row * DFEAT);
        float prod = 1.f;
#pragma unroll
        for (int it = 0; it < DFEAT / (64 * 4); ++it) {   // 8 iters, 1 KiB/instr
            float4 v = xr[it * 64 + lane];
            prod *= (v.x * v.y) * (v.z * v.w);
        }
#pragma unroll
        for (int off = 32; off > 0; off >>= 1)            // wave-wide product
            prod *= __shfl_xor(prod, off);
        if (lane == 0) prodbuf[row] = prod;
        return;
    }

    // ==================== chain block (blockIdx.x < 32) =====================
    const int ri = lane >> 2;             // row 0..15 (this lane's A/F row)
    const int c0 = (lane & 3) << 2;       // col base 0,4,8,12
    const size_t d0 = (size_t)blockIdx.x * CHUNK;

    // ---- per-wave fold of 16 matrices, wave-synchronous (no barriers) ----
    // ALL 16 cores loaded up front into registers (one latency exposure).
    // (lane*4 floats == ri*16 + c0, so the coalesced float4 load per lane
    //  lands exactly at this lane's (ri, c0..c0+3) slot.)
    const float* gw = cores + (d0 + 16 * wave) * NR2;
    float4 pre[16];
#pragma unroll
    for (int t = 0; t < 16; ++t)
        pre[t] = *(const float4*)&gw[(size_t)t * NR2 + lane * 4];

    float* AwW = Abase + wave * 512;      // this wave's A ping-pong (2x256)
    float* BbW = Bbase + wave * 512;      // this wave's core ping-pong (2x256)

    *(float4*)&AwW[0 * 256 + lane * 4] = pre[0];       // A = core0
    int cur = 0;
#pragma unroll
    for (int t = 1; t < 16; ++t) {        // 15 multiplies -> result in buf 1
        *(float4*)&BbW[(t & 1) * 256 + lane * 4] = pre[t];
        float4 r = rowmul(&AwW[cur * 256 + ri * 16], &BbW[(t & 1) * 256], c0);
        *(float4*)&AwW[(cur ^ 1) * 256 + ri * 16 + c0] = r;
        cur ^= 1;
    }
    __syncthreads();                      // all 4 wave-products ready

    // ---- wave 0 combines: F = Aw0 x Aw1 x Aw2 x Aw3 (3 multiplies) ----
    if (wave == 0) {
        *(float4*)&Fbase[0 * 256 + ri * 16 + c0] =
            *(const float4*)&Abase[0 * 512 + 1 * 256 + ri * 16 + c0];
        int cc = 0;
        for (int w = 1; w < 4; ++w) {     // 3 multiplies -> result in F[1]
            float4 r = rowmul(&Fbase[cc * 256 + ri * 16],
                              &Abase[w * 512 + 1 * 256], c0);
            *(float4*)&Fbase[(cc ^ 1) * 256 + ri * 16 + c0] = r;
            cc ^= 1;
        }
    }
    __syncthreads();
    const int i = tid >> 4, j = tid & 15;
    const float v = Fbase[1 * 256 + tid]; // element (i,j) of chunk product
    // >>> Bb/Aw are DEAD from here on: Pt (alias of Bb) may now be written.

    if (blockIdx.x != 0) {
        // ---- producer: publish partial, release flag (verbatim) ----
        partials[blockIdx.x * NR2 + tid] = v;
        __syncthreads();                  // block stores complete at L2
        if (tid == 0)
            __hip_atomic_store(&flags[blockIdx.x], MAGIC,
                               __ATOMIC_RELEASE, __HIP_MEMORY_SCOPE_AGENT);
        return;
    }

    // ---- block 0: own partial straight into LDS slot 0 (transposed) ----
    Pt[0 * 256 + j * 16 + i] = v;

    // acquire-spin for producers 1..31 (every thread: cache-inv side effect)
    // SAFE at this scale: 4 waves spinning, proven rounds 1/2/4.
    {
        const int f = 1 + (tid % (NCHUNK - 1));
        while (__hip_atomic_load(&flags[f], __ATOMIC_ACQUIRE,
                                 __HIP_MEMORY_SCOPE_AGENT) != MAGIC) { }
    }
    __syncthreads();

    // ---- 4 rounds: stage 8 partials transposed (8 KB) + wave-0 fold ----
    float w = 1.f;                        // fold state lives in wave-0 regs
    int E = 0;
    for (int rr = 0; rr < 4; ++rr) {
#pragma unroll
        for (int q = 0; q < 2; ++q) {                 // 512 float4 / round
            const int idx = q * 256 + tid;
            const int flat = idx * 4;
            const int s = flat >> 8;                  // local slot 0..7
            if (rr > 0 || s > 0) {                    // slot 0 of rr=0 = own
                float4 p4 =
                    ((const float4*)(partials + (size_t)(8 * rr) * NR2))[idx];
                const int e = flat & 255;
                const int k = e >> 4, j0 = e & 15;    // row k, cols j0..j0+3
                Pt[s * 256 + (j0 + 0) * 16 + k] = p4.x;
                Pt[s * 256 + (j0 + 1) * 16 + k] = p4.y;
                Pt[s * 256 + (j0 + 2) * 16 + k] = p4.z;
                Pt[s * 256 + (j0 + 3) * 16 + k] = p4.w;
            }
        }
        __syncthreads();
        if (tid < 64) {                   // wave-0 register fold, 8 per round
            const int jj = tid & 15, q = tid >> 4;    // lane = jj + 16*q
            for (int s = 0; s < 8; ++s) {
                const float4 pr = *(const float4*)&Pt[s * 256 + jj * 16 + 4 * q];
                float sum;
                sum = __shfl(w, 4 * q + 0) * pr.x;    // w[k] lives at lane k
                sum = fmaf(__shfl(w, 4 * q + 1), pr.y, sum);
                sum = fmaf(__shfl(w, 4 * q + 2), pr.z, sum);
                sum = fmaf(__shfl(w, 4 * q + 3), pr.w, sum);
                sum += __shfl_xor(sum, 16);           // sum the 4 q-groups
                sum += __shfl_xor(sum, 32);           // -> nw[jj], replicated
                w = sum;
            }
            // renorm once per round (global gg = 8*rr+7 -> gg&7==7, as before)
            float m = fabsf(w);
#pragma unroll
            for (int off = 1; off <= 8; off <<= 1)
                m = fmaxf(m, __shfl_xor(m, off));
            if (m > 0.f) {
                int e2 = 0;
                (void)frexpf(m, &e2);                 // m = f*2^e, f in [.5,1)
                w = ldexpf(w, -e2);                   // exact rescale
                E += e2;
            }
        }
        __syncthreads();                  // Pt reusable next round
    }

    if (tid < 64) {
        // p[o] = sum_k w[k] * proj[k][o]
        float p = 0.f;
#pragma unroll
        for (int k = 0; k < R; ++k)
            p = fmaf(__shfl(w, k), proj[k * OUTD + tid], p);
        pE[tid] = p;
        if (tid == 0) ((int*)pE)[OUTD] = E;
    }
}

// ---------------------------------------------------------------------------
// Epilogue: out[b][o] = ldexp(pE[o] * prod[b], E) + bias[o]. 2 MB coalesced,
// one float4 per thread (512 blocks at B=8192).
// ---------------------------------------------------------------------------
__global__ __launch_bounds__(256) void mps_scale(const float* __restrict__ prodbuf,
                                                 const float* __restrict__ pE,
                                                 const float* __restrict__ bias,
                                                 float* __restrict__ out,
                                                 int B) {
    const int idx = blockIdx.x * 256 + threadIdx.x;   // float4 index
    const int total4 = B * (OUTD / 4);
    if (idx >= total4) return;
    const int row = idx >> 4;             // 16 float4 per row
    const int c4  = idx & 15;
    const float pr = prodbuf[row];
    const int   E  = ((const int*)pE)[OUTD];
    const float4 pe = ((const float4*)pE)[c4];
    const float4 bb = ((const float4*)bias)[c4];
    float4 r;
    r.x = ldexpf(pe.x * pr, E) + bb.x;
    r.y = ldexpf(pe.y * pr, E) + bb.y;
    r.z = ldexpf(pe.z * pr, E) + bb.z;
    r.w = ldexpf(pe.w * pr, E) + bb.w;
    ((float4*)out)[idx] = r;
}

// ---------------------------------------------------------------------------
extern "C" void kernel_launch(void* const* d_in, const int* in_sizes, int n_in,
                              void* d_out, int out_size, void* d_ws, size_t ws_size,
                              hipStream_t stream) {
    const float* inputs = (const float*)d_in[0];   // (B, 2048) fp32
    const float* cores  = (const float*)d_in[1];   // (2048, 16, 16) fp32
    const float* proj   = (const float*)d_in[2];   // (16, 64) fp32
    const float* bias   = (const float*)d_in[3];   // (64,) fp32
    float* out = (float*)d_out;                    // (B, 64) fp32

    const int B = in_sizes[0] / DFEAT;             // 8192

    // ws layout (16B aligned): prodbuf | partials | pE (64f + E) | flags
    float* prodbuf  = (float*)d_ws;                // B floats (32 KiB)
    float* partials = prodbuf + B;                 // 32*256 floats (32 KiB)
    float* pE    = partials + NCHUNK * NR2;        // 64 floats + int E (+pad)
    int*   flags = (int*)(pE + 68);                // 32 ints; harness poison
                                                   // != MAGIC each replay

    const int rowBlocks = (B + 3) / 4;             // 4 rows (waves) per block
    mps_fused<<<NCHUNK + rowBlocks, 256, 0, stream>>>(cores, proj, inputs,
                                                      prodbuf, partials, flags,
                                                      pE, B);
    mps_scale<<<(B * 16 + 255) / 256, 256, 0, stream>>>(prodbuf, pE, bias,
                                                        out, B);
}